// Round 8
// baseline (37.912 us; speedup 1.0000x reference)
//
#include <hip/hip_runtime.h>
#include <hip/hip_fp16.h>
#include <cstddef>
#include <cstdint>

#define D_IN  4096
#define D_OUT 4096
#define BB    64
#define NSUB  8     // sub-bins per floor-col
#define SLOTS 64    // slots per sub-bin: mean 8, P(>64) ~ 0

// ws layout: [cnt: 32K u32 = 128KB][bins: D_OUT*NSUB*SLOTS*8B = 16MB][xP: 2MB]
// ONE 8-byte entry per point, keyed by FLOOR column:
//   .x: rowf[0:11] | rint<<12 | f16(wfr)<<16
//   .y: f16(w_this) | f16(w_next)<<16
// rint = row-is-integer, rowc = rowf+1-rint, wcr = rint ? 1 : 1-wfr,
// w_this = v*wfc (+ v*wcc if integer col), w_next = v*wcc (0 if integer col).
// xP[row][b] = (x[row][b], x[row+1][b])  -> one dwordx2 gather per entry.
// out[c,:] += w_this*term (entries keyed c) + w_next*term (entries keyed c-1),
//   term = wfr*x[rowf,:] + wcr*x[rowc,:]  (integer row -> 2*x[rowf,:] via p.x twice).

// ---------------------------------------------------------------------------
// Phase 0: zero cnt + out, and build xP pair-packed gather table (one kernel).
// ---------------------------------------------------------------------------
__global__ __launch_bounds__(256) void prep_kernel(
    const float* __restrict__ x, uint32_t* __restrict__ cnt,
    float* __restrict__ out, float2* __restrict__ xP) {
  int i = blockIdx.x * 256 + threadIdx.x;     // 0 .. 262143
  if (i < D_OUT * NSUB) cnt[i] = 0u;
  out[i] = 0.f;
  float a = x[i];
  float b = (i + BB < D_IN * BB) ? x[i + BB] : 0.f;
  xP[i] = make_float2(a, b);
}

// ---------------------------------------------------------------------------
// Phase 1: one 8B entry per point into bins[floor_col][sub].
// 262K returning atomics (~10 us empirical floor) + 262K 8B scattered stores.
// ---------------------------------------------------------------------------
__global__ __launch_bounds__(256) void bin_kernel(
    const float2* __restrict__ ind, const float* __restrict__ val,
    uint32_t* __restrict__ cnt, uint2* __restrict__ bins, int n) {
  int i = blockIdx.x * 256 + threadIdx.x;
  if (i >= n) return;
  const int sub = blockIdx.x & (NSUB - 1);
  float2 rc = ind[i];
  float v = val[i];
  float flr = floorf(rc.x), cer = ceilf(rc.x);
  float flc = floorf(rc.y), cec = ceilf(rc.y);
  // reference weight: prod_k (1 - |corner_k - ind_k|)
  float wfr = 1.0f - (rc.x - flr);
  float wfc = 1.0f - (rc.y - flc);
  float wcc = 1.0f - (cec - rc.y);
  uint32_t rint = ((int)flr == (int)cer) ? 1u : 0u;
  bool cint = ((int)flc == (int)cec);
  float w_this = cint ? v * (wfc + wcc) : v * wfc;
  float w_next = cint ? 0.f : v * wcc;
  uint32_t ex = (uint32_t)(int)flr | (rint << 12)
              | ((uint32_t)__half_as_ushort(__float2half_rn(wfr)) << 16);
  uint32_t ey = (uint32_t)__half_as_ushort(__float2half_rn(w_this))
              | ((uint32_t)__half_as_ushort(__float2half_rn(w_next)) << 16);
  int b = ((int)flc) * NSUB + sub;
  uint32_t s = atomicAdd(&cnt[b], 1u);
  if (s < SLOTS) bins[(size_t)b * SLOTS + s] = make_uint2(ex, ey);
}

// ---------------------------------------------------------------------------
// Phase 2: 1 column per block, 4 waves x 2 subs, lane = b. Single visit per
// entry, ONE float2 gather per entry (row pair), 8-deep entry prefetch.
// LDS-reduce across waves, 2 atomicAdds into pre-zeroed out per block.
// ---------------------------------------------------------------------------
__global__ __launch_bounds__(256) void accum_kernel(
    const uint32_t* __restrict__ cnt, const uint2* __restrict__ bins,
    const float2* __restrict__ xP, float* __restrict__ out) {
  __shared__ float red_t[3][BB], red_n[3][BB];
  const int tid  = threadIdx.x;
  const int lane = tid & 63;
  const int wv   = tid >> 6;      // 0..3
  const int col  = blockIdx.x;

  float acc_t = 0.f, acc_n = 0.f;

#define PROC(Q)                                                           \
  {                                                                       \
    uint32_t ex_ = (Q).x, ey_ = (Q).y;                                    \
    int rowf = (int)(ex_ & 0xfffu);                                       \
    int rint = (int)((ex_ >> 12) & 1u);                                   \
    float wfr = __half2float(__ushort_as_half((ushort)(ex_ >> 16)));      \
    float2 p  = xP[(size_t)rowf * BB + lane];                             \
    float xc  = rint ? p.x : p.y;                                         \
    float wcr = rint ? 1.0f : 1.0f - wfr;                                 \
    float w_t = __half2float(__ushort_as_half((ushort)(ey_ & 0xffffu)));  \
    float w_n = __half2float(__ushort_as_half((ushort)(ey_ >> 16)));      \
    float term = fmaf(wfr, p.x, wcr * xc);                                \
    acc_t = fmaf(w_t, term, acc_t);                                       \
    acc_n = fmaf(w_n, term, acc_n);                                       \
  }

#pragma unroll
  for (int s = 0; s < 2; ++s) {
    const int bidx = __builtin_amdgcn_readfirstlane(col * NSUB + wv * 2 + s);
    int n = (int)cnt[bidx];
    n = n < SLOTS ? n : SLOTS;
    const uint2* __restrict__ bin = bins + (size_t)bidx * SLOTS;
    int e = 0;
    while (e + 8 <= n) {
      uint2 q[8];
#pragma unroll
      for (int t = 0; t < 8; t++) q[t] = bin[e + t];
#pragma unroll
      for (int t = 0; t < 8; t++) PROC(q[t]);
      e += 8;
    }
    for (; e < n; e++) {
      uint2 q = bin[e];
      PROC(q)
    }
  }
#undef PROC

  if (wv > 0) {
    red_t[wv - 1][lane] = acc_t;
    red_n[wv - 1][lane] = acc_n;
  }
  __syncthreads();
  if (wv == 0) {
    acc_t += red_t[0][lane] + red_t[1][lane] + red_t[2][lane];
    acc_n += red_n[0][lane] + red_n[1][lane] + red_n[2][lane];
    atomicAdd(&out[(size_t)col * BB + lane], acc_t);
    if (col + 1 < D_OUT) atomicAdd(&out[(size_t)(col + 1) * BB + lane], acc_n);
  }
}

// ---------------------------------------------------------------------------
// Fallback (ws too small): direct atomic scatter into out (f32).
// ---------------------------------------------------------------------------
__global__ __launch_bounds__(256) void direct_kernel(
    const float2* __restrict__ ind, const float* __restrict__ val,
    const float* __restrict__ x, float* __restrict__ out, int n) {
  int p = blockIdx.x * 4 + (threadIdx.x >> 6);
  if (p >= n) return;
  int lane = threadIdx.x & 63;
  float2 rc = ind[p];
  float v = val[p];
  float flr = floorf(rc.x), cer = ceilf(rc.x);
  float flc = floorf(rc.y), cec = ceilf(rc.y);
  float wfr = 1.0f - (rc.x - flr);
  float wcr = 1.0f - (cer - rc.x);
  float wfc = 1.0f - (rc.y - flc);
  float wcc = 1.0f - (cec - rc.y);
  float xf = x[(size_t)((int)flr) * BB + lane];
  float xc = x[(size_t)((int)cer) * BB + lane];
  float inner = fmaf(wfr, xf, wcr * xc);
  atomicAdd(&out[(size_t)((int)flc) * BB + lane], v * wfc * inner);
  atomicAdd(&out[(size_t)((int)cec) * BB + lane], v * wcc * inner);
}

// ---------------------------------------------------------------------------
extern "C" void kernel_launch(void* const* d_in, const int* in_sizes, int n_in,
                              void* d_out, int out_size, void* d_ws, size_t ws_size,
                              hipStream_t stream) {
  const float2* ind = (const float2*)d_in[0];   // [N,2] f32
  const float*  val = (const float*)d_in[1];    // [N]   f32
  const float*  x   = (const float*)d_in[2];    // [D_IN*B] f32
  float* out = (float*)d_out;                   // [D_OUT*B] f32
  const int N = in_sizes[1];

  const size_t cnt_bytes = (size_t)D_OUT * NSUB * sizeof(uint32_t);       // 128 KB
  const size_t bin_bytes = (size_t)D_OUT * NSUB * SLOTS * sizeof(uint2);  // 16 MB
  const size_t xp_bytes  = (size_t)D_IN * BB * sizeof(float2);            // 2 MB

  if (ws_size >= cnt_bytes + bin_bytes + xp_bytes) {
    uint32_t* cnt = (uint32_t*)d_ws;
    uint2* bins = (uint2*)((char*)d_ws + cnt_bytes);
    float2* xP = (float2*)((char*)d_ws + cnt_bytes + bin_bytes);
    prep_kernel<<<(D_IN * BB) / 256, 256, 0, stream>>>(x, cnt, out, xP);
    bin_kernel<<<(N + 255) / 256, 256, 0, stream>>>(ind, val, cnt, bins, N);
    accum_kernel<<<D_OUT, 256, 0, stream>>>(cnt, bins, xP, out);
  } else {
    (void)hipMemsetAsync(out, 0, (size_t)out_size * sizeof(float), stream);
    direct_kernel<<<(N + 3) / 4, 256, 0, stream>>>(ind, val, x, out, N);
  }
}